// Round 7
// baseline (90.030 us; speedup 1.0000x reference)
//
#include <hip/hip_runtime.h>
#include <hip/hip_bf16.h>

typedef short bf16x8 __attribute__((ext_vector_type(8)));
typedef float f32x4  __attribute__((ext_vector_type(4)));

// RNE f32->bf16 (pre-kernels only)
__device__ inline ushort f2bf(float f) {
    union { float f; uint u; } v; v.f = f;
    uint r = (v.u + 0x7FFFu + ((v.u >> 16) & 1u)) >> 16;
    return (ushort)r;
}
// pair convert -> v_cvt_pk_bf16_f32
__device__ inline uint packbf(float a, float b) {
    float2 t; t.x = a; t.y = b;
    __hip_bfloat162 h = __float22bfloat162_rn(t);
    union { __hip_bfloat162 h; uint u; } cv; cv.h = h; return cv.u;
}

// ---- pre-kernel A: pack x rows: [f0..f4, 1.0, 0, 0] bf16; row N = zeros ----
__global__ __launch_bounds__(256) void pack_x_kernel(
    const float* __restrict__ x, uint4* __restrict__ xp, int N)
{
    int i = blockIdx.x * blockDim.x + threadIdx.x;
    if (i > N) return;
    uint4 o = {0u, 0u, 0u, 0u};
    if (i < N) {
        const float* r = x + (size_t)i * 5;
        o.x = packbf(r[0], r[1]);
        o.y = packbf(r[2], r[3]);
        o.z = packbf(r[4], 1.0f);   // slot 5 = 1.0 : bias enabler
    }
    xp[i] = o;
}

// ---- pre-kernel B: per-lane fragment table (14 chunks x 64 lanes x 16B) ----
// chunk 0..3  : W1^T A-frags (EF k-layout, b1 at k=5, h1[50]:=1 enabler)
// chunk 4..11 : W2^T A-frags, formal-K perm sigma; hid1==50 := b2
// chunk 12..13: W3 A-frags (row 0 only), same sigma on k
__global__ __launch_bounds__(64) void pack_w_kernel(
    const float* __restrict__ W1, const float* __restrict__ b1,
    const float* __restrict__ W2, const float* __restrict__ b2,
    const float* __restrict__ W3, uint4* __restrict__ tab)
{
    const int lane = threadIdx.x;       // one wave
    const int c = lane & 15;
    const int g = lane >> 4;

    union { ushort s[8]; uint4 q; } u;
    #pragma unroll
    for (int mt = 0; mt < 4; ++mt) {
        #pragma unroll
        for (int d = 0; d < 8; ++d) {
            int k = 8 * g + d;
            int j = 16 * mt + c;
            float v = 0.f;
            if (j < 50) {
                if (k < 5)                 v = W1[k * 50 + j];
                else if (k == 5)           v = b1[j];
                else if (k >= 8 && k < 13) v = W1[(k - 3) * 50 + j];
            } else if (j == 50 && k == 5)  v = 1.0f;
            u.s[d] = f2bf(v);
        }
        tab[mt * 64 + lane] = u.q;
    }
    #pragma unroll
    for (int t = 0; t < 2; ++t) {
        #pragma unroll
        for (int mt = 0; mt < 4; ++mt) {
            #pragma unroll
            for (int d = 0; d < 8; ++d) {
                int hid1 = 16 * (2 * t + (d >> 2)) + 4 * g + (d & 3);
                int j    = 16 * mt + c;
                float v = 0.f;
                if (j < 50) {
                    if (hid1 < 50)       v = W2[hid1 * 50 + j];
                    else if (hid1 == 50) v = b2[j];
                }
                u.s[d] = f2bf(v);
            }
            tab[(4 + t * 4 + mt) * 64 + lane] = u.q;
        }
    }
    #pragma unroll
    for (int t = 0; t < 2; ++t) {
        #pragma unroll
        for (int d = 0; d < 8; ++d) {
            int hid = 16 * (2 * t + (d >> 2)) + 4 * g + (d & 3);
            float v = (c == 0 && hid < 50) ? W3[hid] : 0.f;
            u.s[d] = f2bf(v);
        }
        tab[(12 + t) * 64 + lane] = u.q;
    }
}

// ---- main: 64 edges/wave (4 subtiles), prefetched gather, 3 MFMA layers ----
__global__ __launch_bounds__(256, 4) void edge_mlp_mfma5(
    const uint4* __restrict__ xp,
    const uint4* __restrict__ wtab,
    const int* __restrict__ ei,
    const float* __restrict__ b3,
    float* __restrict__ out, int E, int N, int num_tiles)
{
    __shared__ uint4 lds_frag[896];     // 14 KB

    const int tid = threadIdx.x;
    for (int i = tid; i < 896; i += 256) lds_frag[i] = wtab[i];
    __syncthreads();

    const int w    = tid >> 6;
    const int lane = tid & 63;
    const int c    = lane & 15;
    const int g    = lane >> 4;

    bf16x8 w1f[4];
    #pragma unroll
    for (int mt = 0; mt < 4; ++mt)
        w1f[mt] = *(const bf16x8*)&lds_frag[mt * 64 + lane];
    bf16x8 w2f[2][4];
    #pragma unroll
    for (int t = 0; t < 2; ++t)
        #pragma unroll
        for (int mt = 0; mt < 4; ++mt)
            w2f[t][mt] = *(const bf16x8*)&lds_frag[(4 + t * 4 + mt) * 64 + lane];
    bf16x8 w3f[2];
    #pragma unroll
    for (int t = 0; t < 2; ++t)
        w3f[t] = *(const bf16x8*)&lds_frag[(12 + t) * 64 + lane];
    const float b3s = b3[0];

    // fragment gather for tile bt_: lane (c, g<2) <- xp[ei[g*E + e]]; g>=2 zero
    auto LOADF = [&](int bt_, bf16x8* a) {
        const int e0 = bt_ * 256 + w * 64;
        #pragma unroll
        for (int ms = 0; ms < 4; ++ms) {
            bf16x8 v = {0, 0, 0, 0, 0, 0, 0, 0};
            if (g < 2) {
                int e  = e0 + ms * 16 + c;
                int ee = (e < E) ? e : 0;
                int idx = ei[(size_t)g * (size_t)E + (size_t)ee];
                union { uint4 q; bf16x8 b; } u;
                u.q = xp[idx];
                v = u.b;
            }
            a[ms] = v;
        }
    };

    int bt = blockIdx.x;
    if (bt >= num_tiles) return;

    bf16x8 aN[4];
    LOADF(bt, aN);

    for (; bt < num_tiles; bt += gridDim.x) {
        bf16x8 aC[4];
        #pragma unroll
        for (int i = 0; i < 4; ++i) aC[i] = aN[i];
        const int btn = bt + gridDim.x;
        if (btn < num_tiles) LOADF(btn, aN);   // hide gather under compute

        const int e0 = bt * 256 + w * 64;

        #pragma unroll
        for (int ms = 0; ms < 4; ++ms) {
            // ---- layer 1 (+b1 folded): h1^T = W1ext^T @ EF^T ----
            f32x4 hT[4];
            #pragma unroll
            for (int mt = 0; mt < 4; ++mt) {
                f32x4 z = {0.f, 0.f, 0.f, 0.f};
                hT[mt] = __builtin_amdgcn_mfma_f32_16x16x32_bf16(w1f[mt], aC[ms], z, 0, 0, 0);
            }
            // relu + pack -> layer-2 B-frags (sigma baked into W2 frags)
            uint pk[4][2];
            #pragma unroll
            for (int mt = 0; mt < 4; ++mt) {
                float v0 = fmaxf(hT[mt][0], 0.f);
                float v1 = fmaxf(hT[mt][1], 0.f);
                float v2 = fmaxf(hT[mt][2], 0.f);
                float v3 = fmaxf(hT[mt][3], 0.f);
                pk[mt][0] = packbf(v0, v1);
                pk[mt][1] = packbf(v2, v3);
            }
            union { uint u[4]; bf16x8 v; } uu;
            uu.u[0] = pk[0][0]; uu.u[1] = pk[0][1];
            uu.u[2] = pk[1][0]; uu.u[3] = pk[1][1];
            bf16x8 bB0 = uu.v;
            uu.u[0] = pk[2][0]; uu.u[1] = pk[2][1];
            uu.u[2] = pk[3][0]; uu.u[3] = pk[3][1];
            bf16x8 bB1 = uu.v;

            // ---- layer 2 (+b2 folded): h2^T = W2ext^T @ h1^T ----
            f32x4 h2T[4];
            #pragma unroll
            for (int mt = 0; mt < 4; ++mt) {
                f32x4 z = {0.f, 0.f, 0.f, 0.f};
                h2T[mt] = __builtin_amdgcn_mfma_f32_16x16x32_bf16(w2f[0][mt], bB0, z, 0, 0, 0);
                h2T[mt] = __builtin_amdgcn_mfma_f32_16x16x32_bf16(w2f[1][mt], bB1, h2T[mt], 0, 0, 0);
            }
            // relu + pack -> layer-3 B-frags (same sigma)
            #pragma unroll
            for (int mt = 0; mt < 4; ++mt) {
                float v0 = fmaxf(h2T[mt][0], 0.f);
                float v1 = fmaxf(h2T[mt][1], 0.f);
                float v2 = fmaxf(h2T[mt][2], 0.f);
                float v3 = fmaxf(h2T[mt][3], 0.f);
                pk[mt][0] = packbf(v0, v1);
                pk[mt][1] = packbf(v2, v3);
            }
            uu.u[0] = pk[0][0]; uu.u[1] = pk[0][1];
            uu.u[2] = pk[1][0]; uu.u[3] = pk[1][1];
            bf16x8 cB0 = uu.v;
            uu.u[0] = pk[2][0]; uu.u[1] = pk[2][1];
            uu.u[2] = pk[3][0]; uu.u[3] = pk[3][1];
            bf16x8 cB1 = uu.v;

            // ---- layer 3 as MFMA: row 0 of C = W3 . relu(h2) ----
            f32x4 z3 = {0.f, 0.f, 0.f, 0.f};
            f32x4 o3 = __builtin_amdgcn_mfma_f32_16x16x32_bf16(w3f[0], cB0, z3, 0, 0, 0);
            o3 = __builtin_amdgcn_mfma_f32_16x16x32_bf16(w3f[1], cB1, o3, 0, 0, 0);

            if (g == 0) {                      // C row 0 lives in lanes 0..15, reg 0
                int e = e0 + ms * 16 + c;
                if (e < E) {
                    float zz = o3[0] + b3s;
                    out[e] = 1.f / (1.f + __expf(-zz));
                }
            }
        }
    }
}

extern "C" void kernel_launch(void* const* d_in, const int* in_sizes, int n_in,
                              void* d_out, int out_size, void* d_ws, size_t ws_size,
                              hipStream_t stream) {
    const float* x  = (const float*)d_in[0];
    const int*   ei = (const int*)d_in[1];
    const float* W1 = (const float*)d_in[2];
    const float* b1 = (const float*)d_in[3];
    const float* W2 = (const float*)d_in[4];
    const float* b2 = (const float*)d_in[5];
    const float* W3 = (const float*)d_in[6];
    const float* b3 = (const float*)d_in[7];
    float* out = (float*)d_out;

    int E = in_sizes[1] / 2;      // edge_index is [2, E]
    int N = in_sizes[0] / 5;      // nodes

    uint4* wtab = (uint4*)d_ws;                    // 14 KB fragment table
    uint4* xp   = (uint4*)((char*)d_ws + 16384);   // (N+1) * 16 B packed x

    pack_w_kernel<<<1, 64, 0, stream>>>(W1, b1, W2, b2, W3, wtab);
    pack_x_kernel<<<(N + 1 + 255) / 256, 256, 0, stream>>>(x, xp, N);

    int num_tiles = (E + 255) / 256;               // 256 edges per block-tile
    int grid = num_tiles < 2048 ? num_tiles : 2048;
    edge_mlp_mfma5<<<grid, 256, 0, stream>>>(xp, wtab, ei, b3, out, E, N, num_tiles);
}

// Round 8
// 76.761 us; speedup vs baseline: 1.1729x; 1.1729x over previous
//
#include <hip/hip_runtime.h>
#include <hip/hip_bf16.h>

typedef short bf16x8 __attribute__((ext_vector_type(8)));
typedef float f32x4  __attribute__((ext_vector_type(4)));

union fragU { f32x4 f; bf16x8 b; uint4 q; uint u[4]; };

// RNE f32->bf16 (pre-kernels only)
__device__ inline ushort f2bf(float f) {
    union { float f; uint u; } v; v.f = f;
    uint r = (v.u + 0x7FFFu + ((v.u >> 16) & 1u)) >> 16;
    return (ushort)r;
}
__device__ inline uint packbf(float a, float b) {
    return (uint)f2bf(a) | ((uint)f2bf(b) << 16);
}
// hot path: single-instruction pack (RNE), lo = first arg
__device__ inline uint cvtpk(float lo, float hi) {
    uint r;
    asm("v_cvt_pk_bf16_f32 %0, %1, %2" : "=v"(r) : "v"(lo), "v"(hi));
    return r;
}

// ---- pre-kernel A: pack x rows: [f0..f4, 1.0, 0, 0] bf16; row N = zeros ----
__global__ __launch_bounds__(256) void pack_x_kernel(
    const float* __restrict__ x, uint4* __restrict__ xp, int N)
{
    int i = blockIdx.x * blockDim.x + threadIdx.x;
    if (i > N) return;
    uint4 o = {0u, 0u, 0u, 0u};
    if (i < N) {
        const float* r = x + (size_t)i * 5;
        o.x = packbf(r[0], r[1]);
        o.y = packbf(r[2], r[3]);
        o.z = packbf(r[4], 1.0f);   // slot 5 = 1.0 : bias enabler
    }
    xp[i] = o;
}

// ---- pre-kernel B: per-lane fragment table (14 chunks x 64 lanes x 16B) ----
// chunk 0..3  : W1^T A-frags (EF k-layout, b1 at k=5, h1[50]:=1 enabler)
// chunk 4..11 : W2^T A-frags, formal-K perm sigma; hid1==50 := b2
// chunk 12..13: W3 A-frags (row 0 only), same sigma on k
__global__ __launch_bounds__(64) void pack_w_kernel(
    const float* __restrict__ W1, const float* __restrict__ b1,
    const float* __restrict__ W2, const float* __restrict__ b2,
    const float* __restrict__ W3, uint4* __restrict__ tab)
{
    const int lane = threadIdx.x;       // one wave
    const int c = lane & 15;
    const int g = lane >> 4;

    union { ushort s[8]; uint4 q; } u;
    #pragma unroll
    for (int mt = 0; mt < 4; ++mt) {
        #pragma unroll
        for (int d = 0; d < 8; ++d) {
            int k = 8 * g + d;
            int j = 16 * mt + c;
            float v = 0.f;
            if (j < 50) {
                if (k < 5)                 v = W1[k * 50 + j];
                else if (k == 5)           v = b1[j];
                else if (k >= 8 && k < 13) v = W1[(k - 3) * 50 + j];
            } else if (j == 50 && k == 5)  v = 1.0f;
            u.s[d] = f2bf(v);
        }
        tab[mt * 64 + lane] = u.q;
    }
    #pragma unroll
    for (int t = 0; t < 2; ++t) {
        #pragma unroll
        for (int mt = 0; mt < 4; ++mt) {
            #pragma unroll
            for (int d = 0; d < 8; ++d) {
                int hid1 = 16 * (2 * t + (d >> 2)) + 4 * g + (d & 3);
                int j    = 16 * mt + c;
                float v = 0.f;
                if (j < 50) {
                    if (hid1 < 50)       v = W2[hid1 * 50 + j];
                    else if (hid1 == 50) v = b2[j];
                }
                u.s[d] = f2bf(v);
            }
            tab[(4 + t * 4 + mt) * 64 + lane] = u.q;
        }
    }
    #pragma unroll
    for (int t = 0; t < 2; ++t) {
        #pragma unroll
        for (int d = 0; d < 8; ++d) {
            int hid = 16 * (2 * t + (d >> 2)) + 4 * g + (d & 3);
            float v = (c == 0 && hid < 50) ? W3[hid] : 0.f;
            u.s[d] = f2bf(v);
        }
        tab[(12 + t) * 64 + lane] = u.q;
    }
}

// ---- main: 32 edges/wave, weights PINNED in VGPRs, prefetched gather ----
__global__ __launch_bounds__(256, 3) void edge_mlp_mfma6(
    const uint4* __restrict__ xp,
    const uint4* __restrict__ wtab,
    const int* __restrict__ ei,
    const float* __restrict__ b3,
    float* __restrict__ out, int E, int N, int num_tiles)
{
    const int tid  = threadIdx.x;
    const int w    = tid >> 6;
    const int lane = tid & 63;
    const int c    = lane & 15;
    const int g    = lane >> 4;

    // one-time coalesced fragment load from baked table
    fragU w1f[4], w2f[8], w3f[2];
    #pragma unroll
    for (int i = 0; i < 4; ++i) w1f[i].q = wtab[i * 64 + lane];
    #pragma unroll
    for (int i = 0; i < 8; ++i) w2f[i].q = wtab[(4 + i) * 64 + lane];
    #pragma unroll
    for (int i = 0; i < 2; ++i) w3f[i].q = wtab[(12 + i) * 64 + lane];

    // PIN: opaque to the optimizer -> cannot re-load or rematerialize;
    // 56 VGPRs stay resident for the whole kernel.
    asm volatile("" :
        "+v"(w1f[0].f), "+v"(w1f[1].f), "+v"(w1f[2].f), "+v"(w1f[3].f),
        "+v"(w2f[0].f), "+v"(w2f[1].f), "+v"(w2f[2].f), "+v"(w2f[3].f),
        "+v"(w2f[4].f), "+v"(w2f[5].f), "+v"(w2f[6].f), "+v"(w2f[7].f),
        "+v"(w3f[0].f), "+v"(w3f[1].f));

    const float b3s = b3[0];

    // fragment gather for tile bt_: lane (c, g<2) <- xp[ei[g*E + e]]; g>=2 zero
    auto LOADF = [&](int bt_, fragU* a) {
        const int e0 = bt_ * 128 + w * 32;
        #pragma unroll
        for (int ms = 0; ms < 2; ++ms) {
            uint4 q = {0u, 0u, 0u, 0u};
            if (g < 2) {
                int e  = e0 + ms * 16 + c;
                int ee = (e < E) ? e : 0;
                int idx = ei[(size_t)g * (size_t)E + (size_t)ee];
                q = xp[idx];
            }
            a[ms].q = q;
        }
    };

    int bt = blockIdx.x;
    if (bt >= num_tiles) return;

    fragU aN[2];
    LOADF(bt, aN);

    for (; bt < num_tiles; bt += gridDim.x) {
        fragU aC[2];
        aC[0] = aN[0];
        aC[1] = aN[1];
        const int btn = bt + gridDim.x;
        if (btn < num_tiles) LOADF(btn, aN);     // hide gather under compute

        const int e0 = bt * 128 + w * 32;

        #pragma unroll
        for (int ms = 0; ms < 2; ++ms) {
            // ---- layer 1 (+b1 folded): h1^T = W1ext^T @ EF^T ----
            f32x4 hT[4];
            #pragma unroll
            for (int mt = 0; mt < 4; ++mt) {
                f32x4 z = {0.f, 0.f, 0.f, 0.f};
                hT[mt] = __builtin_amdgcn_mfma_f32_16x16x32_bf16(w1f[mt].b, aC[ms].b, z, 0, 0, 0);
            }
            // relu + 1-instr pack -> layer-2 B-frags (sigma baked into W2 frags)
            fragU bB0, bB1;
            #pragma unroll
            for (int mt = 0; mt < 2; ++mt) {
                bB0.u[2*mt]   = cvtpk(fmaxf(hT[mt][0], 0.f), fmaxf(hT[mt][1], 0.f));
                bB0.u[2*mt+1] = cvtpk(fmaxf(hT[mt][2], 0.f), fmaxf(hT[mt][3], 0.f));
                bB1.u[2*mt]   = cvtpk(fmaxf(hT[2+mt][0], 0.f), fmaxf(hT[2+mt][1], 0.f));
                bB1.u[2*mt+1] = cvtpk(fmaxf(hT[2+mt][2], 0.f), fmaxf(hT[2+mt][3], 0.f));
            }

            // ---- layer 2 (+b2 folded): h2^T = W2ext^T @ h1^T ----
            f32x4 h2T[4];
            #pragma unroll
            for (int mt = 0; mt < 4; ++mt) {
                f32x4 z = {0.f, 0.f, 0.f, 0.f};
                h2T[mt] = __builtin_amdgcn_mfma_f32_16x16x32_bf16(w2f[mt].b,     bB0.b, z, 0, 0, 0);
                h2T[mt] = __builtin_amdgcn_mfma_f32_16x16x32_bf16(w2f[4 + mt].b, bB1.b, h2T[mt], 0, 0, 0);
            }
            // relu + pack -> layer-3 B-frags (same sigma)
            fragU cB0, cB1;
            #pragma unroll
            for (int mt = 0; mt < 2; ++mt) {
                cB0.u[2*mt]   = cvtpk(fmaxf(h2T[mt][0], 0.f), fmaxf(h2T[mt][1], 0.f));
                cB0.u[2*mt+1] = cvtpk(fmaxf(h2T[mt][2], 0.f), fmaxf(h2T[mt][3], 0.f));
                cB1.u[2*mt]   = cvtpk(fmaxf(h2T[2+mt][0], 0.f), fmaxf(h2T[2+mt][1], 0.f));
                cB1.u[2*mt+1] = cvtpk(fmaxf(h2T[2+mt][2], 0.f), fmaxf(h2T[2+mt][3], 0.f));
            }

            // ---- layer 3 as MFMA: C row 0 = W3 . relu(h2) ----
            f32x4 z3 = {0.f, 0.f, 0.f, 0.f};
            f32x4 o3 = __builtin_amdgcn_mfma_f32_16x16x32_bf16(w3f[0].b, cB0.b, z3, 0, 0, 0);
            o3 = __builtin_amdgcn_mfma_f32_16x16x32_bf16(w3f[1].b, cB1.b, o3, 0, 0, 0);

            if (g == 0) {                  // C row 0 -> lanes 0..15, reg 0
                int e = e0 + ms * 16 + c;
                if (e < E) {
                    float zz = o3[0] + b3s;
                    out[e] = 1.f / (1.f + __expf(-zz));
                }
            }
        }
    }
}

extern "C" void kernel_launch(void* const* d_in, const int* in_sizes, int n_in,
                              void* d_out, int out_size, void* d_ws, size_t ws_size,
                              hipStream_t stream) {
    const float* x  = (const float*)d_in[0];
    const int*   ei = (const int*)d_in[1];
    const float* W1 = (const float*)d_in[2];
    const float* b1 = (const float*)d_in[3];
    const float* W2 = (const float*)d_in[4];
    const float* b2 = (const float*)d_in[5];
    const float* W3 = (const float*)d_in[6];
    const float* b3 = (const float*)d_in[7];
    float* out = (float*)d_out;

    int E = in_sizes[1] / 2;      // edge_index is [2, E]
    int N = in_sizes[0] / 5;      // nodes

    uint4* wtab = (uint4*)d_ws;                    // 14 KB fragment table
    uint4* xp   = (uint4*)((char*)d_ws + 16384);   // (N+1) * 16 B packed x

    pack_w_kernel<<<1, 64, 0, stream>>>(W1, b1, W2, b2, W3, wtab);
    pack_x_kernel<<<(N + 1 + 255) / 256, 256, 0, stream>>>(x, xp, N);

    int num_tiles = (E + 127) / 128;               // 128 edges per block-tile
    int grid = num_tiles < 2048 ? num_tiles : 2048;
    edge_mlp_mfma6<<<grid, 256, 0, stream>>>(xp, wtab, ei, b3, out, E, N, num_tiles);
}

// Round 9
// 70.592 us; speedup vs baseline: 1.2753x; 1.0874x over previous
//
#include <hip/hip_runtime.h>
#include <hip/hip_bf16.h>

typedef short bf16x8 __attribute__((ext_vector_type(8)));
typedef float f32x4  __attribute__((ext_vector_type(4)));

union fragU { f32x4 f; bf16x8 b; uint4 q; uint u[4]; };

// RNE f32->bf16 (pre-kernels only)
__device__ inline ushort f2bf(float f) {
    union { float f; uint u; } v; v.f = f;
    uint r = (v.u + 0x7FFFu + ((v.u >> 16) & 1u)) >> 16;
    return (ushort)r;
}
__device__ inline uint packbf(float a, float b) {
    return (uint)f2bf(a) | ((uint)f2bf(b) << 16);
}
// hot path: single-instruction pack (RNE), lo = first arg
__device__ inline uint cvtpk(float lo, float hi) {
    uint r;
    asm("v_cvt_pk_bf16_f32 %0, %1, %2" : "=v"(r) : "v"(lo), "v"(hi));
    return r;
}

// ---- pre-kernel A: pack x rows: [f0..f4, 1.0, 0, 0] bf16; row N = zeros ----
__global__ __launch_bounds__(256) void pack_x_kernel(
    const float* __restrict__ x, uint4* __restrict__ xp, int N)
{
    int i = blockIdx.x * blockDim.x + threadIdx.x;
    if (i > N) return;
    uint4 o = {0u, 0u, 0u, 0u};
    if (i < N) {
        const float* r = x + (size_t)i * 5;
        o.x = packbf(r[0], r[1]);
        o.y = packbf(r[2], r[3]);
        o.z = packbf(r[4], 1.0f);   // slot 5 = 1.0 : bias enabler
    }
    xp[i] = o;
}

// ---- pre-kernel B: per-lane fragment table (14 chunks x 64 lanes x 16B) ----
// chunk 0..3  : W1^T A-frags (EF k-layout, b1 at k=5, h1[50]:=1 enabler)
// chunk 4..11 : W2^T A-frags, formal-K perm sigma; hid1==50 := b2
// chunk 12..13: W3 A-frags (row 0 only), same sigma on k
__global__ __launch_bounds__(64) void pack_w_kernel(
    const float* __restrict__ W1, const float* __restrict__ b1,
    const float* __restrict__ W2, const float* __restrict__ b2,
    const float* __restrict__ W3, uint4* __restrict__ tab)
{
    const int lane = threadIdx.x;       // one wave
    const int c = lane & 15;
    const int g = lane >> 4;

    union { ushort s[8]; uint4 q; } u;
    #pragma unroll
    for (int mt = 0; mt < 4; ++mt) {
        #pragma unroll
        for (int d = 0; d < 8; ++d) {
            int k = 8 * g + d;
            int j = 16 * mt + c;
            float v = 0.f;
            if (j < 50) {
                if (k < 5)                 v = W1[k * 50 + j];
                else if (k == 5)           v = b1[j];
                else if (k >= 8 && k < 13) v = W1[(k - 3) * 50 + j];
            } else if (j == 50 && k == 5)  v = 1.0f;
            u.s[d] = f2bf(v);
        }
        tab[mt * 64 + lane] = u.q;
    }
    #pragma unroll
    for (int t = 0; t < 2; ++t) {
        #pragma unroll
        for (int mt = 0; mt < 4; ++mt) {
            #pragma unroll
            for (int d = 0; d < 8; ++d) {
                int hid1 = 16 * (2 * t + (d >> 2)) + 4 * g + (d & 3);
                int j    = 16 * mt + c;
                float v = 0.f;
                if (j < 50) {
                    if (hid1 < 50)       v = W2[hid1 * 50 + j];
                    else if (hid1 == 50) v = b2[j];
                }
                u.s[d] = f2bf(v);
            }
            tab[(4 + t * 4 + mt) * 64 + lane] = u.q;
        }
    }
    #pragma unroll
    for (int t = 0; t < 2; ++t) {
        #pragma unroll
        for (int d = 0; d < 8; ++d) {
            int hid = 16 * (2 * t + (d >> 2)) + 4 * g + (d & 3);
            float v = (c == 0 && hid < 50) ? W3[hid] : 0.f;
            u.s[d] = f2bf(v);
        }
        tab[(12 + t) * 64 + lane] = u.q;
    }
}

// ---- main: 32 edges/wave; weights in LDS; 2-deep decoupled idx/frag pipeline ----
__global__ __launch_bounds__(256, 4) void edge_mlp_mfma7(
    const uint4* __restrict__ xp,
    const uint4* __restrict__ wtab,
    const int* __restrict__ ei,
    const float* __restrict__ b3,
    float* __restrict__ out, int E, int N, int num_tiles)
{
    __shared__ uint4 lds_w[896];        // 14 KB fragment table, lane-indexed

    const int tid = threadIdx.x;
    #pragma unroll
    for (int i = 0; i < 4; ++i) lds_w[tid + 256 * i] = wtab[tid + 256 * i];
    if (tid < 896 - 1024 + 256) { /* no-op, 896<1024 */ }
    // remaining 896-768=128 entries
    if (tid < 128) lds_w[768 + tid] = wtab[768 + tid];
    __syncthreads();

    const int w    = tid >> 6;
    const int lane = tid & 63;
    const int c    = lane & 15;
    const int g    = lane >> 4;
    const int G    = gridDim.x;

    const float b3s = b3[0];

    // idx load for tile bt_ (clamped): lane (c, g<2) holds indices for its 2 subtiles
    auto LOAD_IDX = [&](int bt_) -> int2 {
        int bc = (bt_ < num_tiles) ? bt_ : (num_tiles - 1);
        int2 r; r.x = 0; r.y = 0;
        if (g < 2) {
            const int e0 = bc * 128 + w * 32;
            int eA = e0 + c;      if (eA >= E) eA = 0;
            int eB = e0 + 16 + c; if (eB >= E) eB = 0;
            const int* row = ei + (size_t)g * (size_t)E;
            r.x = row[eA];
            r.y = row[eB];
        }
        return r;
    };
    // fragment gather using resident indices
    auto GATHER = [&](int2 idx, fragU* a) {
        uint4 q0 = {0u,0u,0u,0u}, q1 = {0u,0u,0u,0u};
        if (g < 2) { q0 = xp[idx.x]; q1 = xp[idx.y]; }
        a[0].q = q0; a[1].q = q1;
    };

    // one 16-edge subtile: 3 MFMA layers, weights from LDS
    auto COMP = [&](fragU aX, int e) {
        f32x4 hT[4];
        #pragma unroll
        for (int mt = 0; mt < 4; ++mt) {
            fragU w1; w1.q = lds_w[mt * 64 + lane];
            f32x4 z = {0.f, 0.f, 0.f, 0.f};
            hT[mt] = __builtin_amdgcn_mfma_f32_16x16x32_bf16(w1.b, aX.b, z, 0, 0, 0);
        }
        fragU bB0, bB1;
        #pragma unroll
        for (int mt = 0; mt < 2; ++mt) {
            bB0.u[2*mt]   = cvtpk(fmaxf(hT[mt][0], 0.f),   fmaxf(hT[mt][1], 0.f));
            bB0.u[2*mt+1] = cvtpk(fmaxf(hT[mt][2], 0.f),   fmaxf(hT[mt][3], 0.f));
            bB1.u[2*mt]   = cvtpk(fmaxf(hT[2+mt][0], 0.f), fmaxf(hT[2+mt][1], 0.f));
            bB1.u[2*mt+1] = cvtpk(fmaxf(hT[2+mt][2], 0.f), fmaxf(hT[2+mt][3], 0.f));
        }
        f32x4 h2T[4];
        #pragma unroll
        for (int mt = 0; mt < 4; ++mt) {
            fragU wa, wb;
            wa.q = lds_w[(4 + mt) * 64 + lane];
            wb.q = lds_w[(8 + mt) * 64 + lane];
            f32x4 z = {0.f, 0.f, 0.f, 0.f};
            h2T[mt] = __builtin_amdgcn_mfma_f32_16x16x32_bf16(wa.b, bB0.b, z, 0, 0, 0);
            h2T[mt] = __builtin_amdgcn_mfma_f32_16x16x32_bf16(wb.b, bB1.b, h2T[mt], 0, 0, 0);
        }
        fragU cB0, cB1;
        #pragma unroll
        for (int mt = 0; mt < 2; ++mt) {
            cB0.u[2*mt]   = cvtpk(fmaxf(h2T[mt][0], 0.f),   fmaxf(h2T[mt][1], 0.f));
            cB0.u[2*mt+1] = cvtpk(fmaxf(h2T[mt][2], 0.f),   fmaxf(h2T[mt][3], 0.f));
            cB1.u[2*mt]   = cvtpk(fmaxf(h2T[2+mt][0], 0.f), fmaxf(h2T[2+mt][1], 0.f));
            cB1.u[2*mt+1] = cvtpk(fmaxf(h2T[2+mt][2], 0.f), fmaxf(h2T[2+mt][3], 0.f));
        }
        fragU w3a, w3b;
        w3a.q = lds_w[12 * 64 + lane];
        w3b.q = lds_w[13 * 64 + lane];
        f32x4 z3 = {0.f, 0.f, 0.f, 0.f};
        f32x4 o3 = __builtin_amdgcn_mfma_f32_16x16x32_bf16(w3a.b, cB0.b, z3, 0, 0, 0);
        o3 = __builtin_amdgcn_mfma_f32_16x16x32_bf16(w3b.b, cB1.b, o3, 0, 0, 0);

        if (g == 0 && e < E) {              // C row 0 -> lanes 0..15, reg 0
            float zz = o3[0] + b3s;
            float ex = __expf(-zz);
            out[e] = __builtin_amdgcn_rcpf(1.f + ex);
        }
    };

    int bt = blockIdx.x;
    if (bt >= num_tiles) return;

    // pipeline prologue
    int2 idxC = LOAD_IDX(bt);
    fragU fC[2];
    GATHER(idxC, fC);                 // serial once
    int2 idxN = LOAD_IDX(bt + G);

    for (; bt < num_tiles; bt += G) {
        fragU fN[2];
        GATHER(idxN, fN);             // addresses resident -> no wait to issue
        idxN = LOAD_IDX(bt + 2 * G);  // independent load for t+2

        const int e0 = bt * 128 + w * 32;
        COMP(fC[0], e0 + c);          // waits on nothing (fC resident)
        COMP(fC[1], e0 + 16 + c);

        fC[0] = fN[0];                // vmcnt wait lands here, ~600 cyc after issue
        fC[1] = fN[1];
    }
}

extern "C" void kernel_launch(void* const* d_in, const int* in_sizes, int n_in,
                              void* d_out, int out_size, void* d_ws, size_t ws_size,
                              hipStream_t stream) {
    const float* x  = (const float*)d_in[0];
    const int*   ei = (const int*)d_in[1];
    const float* W1 = (const float*)d_in[2];
    const float* b1 = (const float*)d_in[3];
    const float* W2 = (const float*)d_in[4];
    const float* b2 = (const float*)d_in[5];
    const float* W3 = (const float*)d_in[6];
    const float* b3 = (const float*)d_in[7];
    float* out = (float*)d_out;

    int E = in_sizes[1] / 2;      // edge_index is [2, E]
    int N = in_sizes[0] / 5;      // nodes

    uint4* wtab = (uint4*)d_ws;                    // 14 KB fragment table
    uint4* xp   = (uint4*)((char*)d_ws + 16384);   // (N+1) * 16 B packed x

    pack_w_kernel<<<1, 64, 0, stream>>>(W1, b1, W2, b2, W3, wtab);
    pack_x_kernel<<<(N + 1 + 255) / 256, 256, 0, stream>>>(x, xp, N);

    int num_tiles = (E + 127) / 128;               // 128 edges per block-tile
    int grid = num_tiles < 2048 ? num_tiles : 2048;
    edge_mlp_mfma7<<<grid, 256, 0, stream>>>(xp, wtab, ei, b3, out, E, N, num_tiles);
}